// Round 7
// baseline (529.722 us; speedup 1.0000x reference)
//
#include <hip/hip_runtime.h>
#include <hip/hip_bf16.h>

#define NN 8192
#define KK 32

typedef __attribute__((ext_vector_type(8))) short short8v;   // 8 bf16 in 4 VGPRs
typedef __attribute__((ext_vector_type(4))) float float4v;   // MFMA 16x16 acc

__device__ __forceinline__ float wave_reduce_sum(float v) {
    #pragma unroll
    for (int off = 32; off > 0; off >>= 1) v += __shfl_down(v, off);
    return v;
}
__device__ __forceinline__ float wave_reduce_max(float v) {
    #pragma unroll
    for (int off = 32; off > 0; off >>= 1) v = fmaxf(v, __shfl_down(v, off));
    return v;
}
__device__ __forceinline__ unsigned short f2bf(float x) {  // RNE fp32->bf16
    unsigned int u = __float_as_uint(x);
    return (unsigned short)((u + 0x7fffu + ((u >> 16) & 1u)) >> 16);
}
__device__ __forceinline__ float bf2f(unsigned short h) {
    return __uint_as_float(((unsigned int)h) << 16);
}

// ---------- K0: column softmax stats of C (N x K) — single pass, registers ----------
__global__ void kc_colstats(const float* __restrict__ C, float* __restrict__ mC,
                            float* __restrict__ sC) {
    const int l = blockIdx.x;
    const int t = threadIdx.x;  // 256
    float v[32];
    #pragma unroll
    for (int u = 0; u < 32; ++u)
        v[u] = C[(size_t)(u * 256 + t) * KK + l];
    float m = v[0];
    #pragma unroll
    for (int u = 1; u < 32; ++u) m = fmaxf(m, v[u]);
    m = wave_reduce_max(m);
    __shared__ float wmax[4], wsum[4];
    if ((t & 63) == 0) wmax[t >> 6] = m;
    __syncthreads();
    const float mm = fmaxf(fmaxf(wmax[0], wmax[1]), fmaxf(wmax[2], wmax[3]));
    float s = 0.f;
    #pragma unroll
    for (int u = 0; u < 32; ++u) s += __expf(v[u] - mm);
    s = wave_reduce_sum(s);
    if ((t & 63) == 0) wsum[t >> 6] = s;
    __syncthreads();
    if (t == 0) {
        mC[l] = mm;
        sC[l] = wsum[0] + wsum[1] + wsum[2] + wsum[3];
    }
}

// ---------- K1: column softmax of X (K x N) -> Xs ----------
__global__ void kx_softmax(const float* __restrict__ X, float* __restrict__ Xs) {
    const int n = blockIdx.x * 256 + threadIdx.x;
    float e[KK];
    float m = -INFINITY;
    #pragma unroll
    for (int k = 0; k < KK; ++k) {
        e[k] = X[(size_t)k * NN + n];
        m = fmaxf(m, e[k]);
    }
    float s = 0.f;
    #pragma unroll
    for (int k = 0; k < KK; ++k) {
        e[k] = __expf(e[k] - m);
        s += e[k];
    }
    const float r = 1.f / s;
    #pragma unroll
    for (int k = 0; k < KK; ++k) Xs[(size_t)k * NN + n] = e[k] * r;
}

// ---------- K2: E = Xs @ softmax(C) — 256 blocks, one 32-n tile each ----------
__global__ void ke_E(const float* __restrict__ Xs, const float* __restrict__ C,
                     const float* __restrict__ mC, const float* __restrict__ sC,
                     float* __restrict__ E) {
    __shared__ float xsl[KK * 33];
    __shared__ float cql[32 * 33];
    __shared__ float mCl[KK], rsCl[KK];
    const int tid = threadIdx.x;     // 1024
    if (tid < KK) { mCl[tid] = mC[tid]; rsCl[tid] = 1.f / sC[tid]; }
    const int k = tid & 31, l = tid >> 5;
    const int nb = blockIdx.x * 32;
    __syncthreads();
    xsl[(tid >> 5) * 33 + (tid & 31)] = Xs[(size_t)(tid >> 5) * NN + nb + (tid & 31)];
    const float cv = C[(size_t)nb * KK + tid];
    cql[(tid >> 5) * 33 + (tid & 31)] = __expf(cv - mCl[tid & 31]) * rsCl[tid & 31];
    __syncthreads();
    float acc = 0.f;
    #pragma unroll
    for (int n = 0; n < 32; ++n)
        acc = fmaf(xsl[k * 33 + n], cql[n * 33 + l], acc);
    atomicAdd(&E[k * KK + l], acc);
}

// ---------- K3: M = E^T E ----------
__global__ void km_M(const float* __restrict__ E, float* __restrict__ M) {
    __shared__ float el[KK * 33];
    const int tid = threadIdx.x;   // 1024
    el[(tid >> 5) * 33 + (tid & 31)] = E[tid];
    __syncthreads();
    const int l1 = tid & 31, l2 = tid >> 5;
    float acc = 0.f;
    #pragma unroll
    for (int kk = 0; kk < KK; ++kk)
        acc = fmaf(el[kk * 33 + l1], el[kk * 33 + l2], acc);
    M[tid] = acc;
}

// ---------- K4: per-node prep: f, Xt f32, Xh/Wh bf16 [N][K], Wt2 bf16 [K][N] ----------
__global__ void kp_prep(const float* __restrict__ X, const float* __restrict__ beta,
                        const float* __restrict__ a_ptr, const float* __restrict__ Mm,
                        float* __restrict__ f, float* __restrict__ Xt,
                        unsigned short* __restrict__ Xh, unsigned short* __restrict__ Wh,
                        unsigned short* __restrict__ Wt2,
                        double* __restrict__ acc) {
    __shared__ float Ml[KK * KK];
    const int tid = threadIdx.x;  // 256
    #pragma unroll
    for (int u = 0; u < 4; ++u) Ml[tid + 256 * u] = Mm[tid + 256 * u];
    __syncthreads();
    const int n = blockIdx.x * 256 + tid;
    float x[KK], v[KK];
    #pragma unroll
    for (int k = 0; k < KK; ++k) x[k] = X[(size_t)k * NN + n];
    const float a = a_ptr[0];
    const float two_a = 2.f * a;
    #pragma unroll
    for (int l = 0; l < KK; ++l) {
        float s = 0.f;
        #pragma unroll
        for (int k = 0; k < KK; ++k) s = fmaf(Ml[l * KK + k], x[k], s);
        v[l] = two_a * s;                     // w = 2a M x
    }
    float q2 = 0.f;
    #pragma unroll
    for (int l = 0; l < KK; ++l) q2 = fmaf(x[l], v[l], q2);
    const float b = beta[n];
    const float fn = b - 0.5f * q2;           // f = beta - a x^T M x
    f[n] = fn;

    union PK { unsigned short u[8]; short8v s; };
    PK xh, wh;
    #pragma unroll
    for (int g = 0; g < 4; ++g) {
        #pragma unroll
        for (int e = 0; e < 8; ++e) {
            const int k = g * 8 + e;
            Xt[(size_t)n * KK + k] = x[k];
            xh.u[e] = f2bf(x[k]);
            wh.u[e] = f2bf(v[k]);
            Wt2[(size_t)k * NN + n] = wh.u[e];   // transposed, coalesced per-k
        }
        *(short8v*)&Xh[(size_t)n * KK + g * 8] = xh.s;
        *(short8v*)&Wh[(size_t)n * KK + g * 8] = wh.s;
    }
    // diagonal softplus: theta_ii = 2*beta_i exactly (z_ii = 0)
    const float th = 2.f * b;
    float sp = fmaxf(th, 0.f) + __logf(1.f + __expf(-fabsf(th)));
    sp = wave_reduce_sum(sp);
    if ((tid & 63) == 0) atomicAdd(&acc[2], (double)sp);
}

// ---------- K5: unified kernel. Wave = 64 i-rows x 128 j.
// A-part: P = A@W via MFMA (A-frag native layout, float8 A loads), rowsum*f_i,
// colsum*f_j on the same stream. S-part: softplus over the same region. ----------
__global__ __launch_bounds__(256) void k_uni(
    const float* __restrict__ A, const float* __restrict__ f,
    const float* __restrict__ Xt,
    const unsigned short* __restrict__ Xh, const unsigned short* __restrict__ Wh,
    const unsigned short* __restrict__ Wt2,
    float* __restrict__ part) {
    const int tid  = threadIdx.x;
    const int lane = tid & 63;
    const int l15  = lane & 15;
    const int g4   = lane >> 4;      // 0..3
    const int klo2 = g4 << 3;        // 8-elem group offset (j for A/W frags, k for xh/wh)
    const int r0   = g4 << 2;        // D-layout row group
    const int wid  = blockIdx.x * 4 + (tid >> 6);
    const int ibase = (wid >> 6) << 6;    // 128 i-tiles of 64 rows
    const int jc    = (wid & 63) << 7;    // 64 j-chunks of 128

    float fI[4];
    #pragma unroll
    for (int s = 0; s < 4; ++s) fI[s] = f[ibase + s * 16 + l15];

    float4v pacc[4][2];
    #pragma unroll
    for (int s = 0; s < 4; ++s)
        #pragma unroll
        for (int h = 0; h < 2; ++h)
            pacc[s][h] = (float4v){0.f, 0.f, 0.f, 0.f};
    float accFR = 0.f, accFC = 0.f;

    // ---- A stream: 4 jt of 32 j ----
    #pragma unroll
    for (int jt = 0; jt < 4; ++jt) {
        const int jb = jc + (jt << 5);
        const float4 fj0 = *(const float4*)&f[jb + klo2];
        const float4 fj1 = *(const float4*)&f[jb + klo2 + 4];
        const short8v w0 = *(const short8v*)&Wt2[(size_t)l15 * NN + jb + klo2];
        const short8v w1 = *(const short8v*)&Wt2[(size_t)(16 + l15) * NN + jb + klo2];
        #pragma unroll
        for (int s = 0; s < 4; ++s) {
            const float* ar = &A[(size_t)(ibase + s * 16 + l15) * NN + jb + klo2];
            const float4 a0 = *(const float4*)ar;
            const float4 a1 = *(const float4*)(ar + 4);
            accFR += (((a0.x + a0.y) + (a0.z + a0.w)) +
                      ((a1.x + a1.y) + (a1.z + a1.w))) * fI[s];
            accFC += a0.x * fj0.x + a0.y * fj0.y + a0.z * fj0.z + a0.w * fj0.w +
                     a1.x * fj1.x + a1.y * fj1.y + a1.z * fj1.z + a1.w * fj1.w;
            // pack A to bf16 by truncation (exact for A in {0,1}); v_perm per pair
            union { unsigned int u[4]; short8v s8; } af;
            af.u[0] = __builtin_amdgcn_perm(__float_as_uint(a0.y), __float_as_uint(a0.x), 0x07060302u);
            af.u[1] = __builtin_amdgcn_perm(__float_as_uint(a0.w), __float_as_uint(a0.z), 0x07060302u);
            af.u[2] = __builtin_amdgcn_perm(__float_as_uint(a1.y), __float_as_uint(a1.x), 0x07060302u);
            af.u[3] = __builtin_amdgcn_perm(__float_as_uint(a1.w), __float_as_uint(a1.z), 0x07060302u);
            pacc[s][0] = __builtin_amdgcn_mfma_f32_16x16x32_bf16(af.s8, w0, pacc[s][0], 0, 0, 0);
            pacc[s][1] = __builtin_amdgcn_mfma_f32_16x16x32_bf16(af.s8, w1, pacc[s][1], 0, 0, 0);
        }
    }

    // ---- x . P epilogue (P complete over this wave's j-range) ----
    float accAX = 0.f;
    #pragma unroll
    for (int s = 0; s < 4; ++s)
        #pragma unroll
        for (int h = 0; h < 2; ++h)
            #pragma unroll
            for (int r = 0; r < 4; ++r)
                accAX += Xt[(size_t)(ibase + s * 16 + r0 + r) * KK + h * 16 + l15]
                         * pacc[s][h][r];

    // ---- S-part: softplus over the same 64 x 128 region ----
    short8v xf[4];
    #pragma unroll
    for (int s = 0; s < 4; ++s)
        xf[s] = *(const short8v*)&Xh[(size_t)(ibase + s * 16 + l15) * KK + klo2];
    float fS[4][4];
    #pragma unroll
    for (int s = 0; s < 4; ++s)
        #pragma unroll
        for (int r = 0; r < 4; ++r) fS[s][r] = f[ibase + s * 16 + r0 + r];

    float accS = 0.f;
    #pragma unroll 2
    for (int u = 0; u < 8; ++u) {
        const int jb2 = jc + (u << 4);
        const short8v wf = *(const short8v*)&Wh[(size_t)(jb2 + l15) * KK + klo2];
        const float fj = f[jb2 + l15];
        #pragma unroll
        for (int s = 0; s < 4; ++s) {
            float4v d = {0.f, 0.f, 0.f, 0.f};
            d = __builtin_amdgcn_mfma_f32_16x16x32_bf16(xf[s], wf, d, 0, 0, 0);
            #pragma unroll
            for (int r = 0; r < 4; ++r) {
                const float th = fS[s][r] + fj + d[r];
                accS += fmaxf(th, 0.f) + __logf(1.f + __expf(-fabsf(th)));
            }
        }
    }

    float accA = accFR + accFC + accAX;
    accA = wave_reduce_sum(accA);
    accS = wave_reduce_sum(accS);
    __shared__ float rA[4], rS[4];
    if (lane == 0) { rA[tid >> 6] = accA; rS[tid >> 6] = accS; }
    __syncthreads();
    if (tid == 0) {
        part[blockIdx.x * 2]     = rA[0] + rA[1] + rA[2] + rA[3];
        part[blockIdx.x * 2 + 1] = rS[0] + rS[1] + rS[2] + rS[3];
    }
}

// ---------- K6: final deterministic reduction of 2048 block partials ----------
__global__ __launch_bounds__(1024) void kz_final(const float* __restrict__ part,
                                                 const double* __restrict__ acc,
                                                 float* __restrict__ out) {
    const int t = threadIdx.x;  // 1024 threads, 16 waves
    double dA = (double)part[2 * t]     + (double)part[2 * (t + 1024)];
    double dS = (double)part[2 * t + 1] + (double)part[2 * (t + 1024) + 1];
    #pragma unroll
    for (int off = 32; off > 0; off >>= 1) {
        dA += __shfl_down(dA, off);
        dS += __shfl_down(dS, off);
    }
    __shared__ double sA[16], sS[16];
    if ((t & 63) == 0) { sA[t >> 6] = dA; sS[t >> 6] = dS; }
    __syncthreads();
    if (t == 0) {
        double a = 0.0, s = 0.0;
        #pragma unroll
        for (int u = 0; u < 16; ++u) { a += sA[u]; s += sS[u]; }
        out[0] = (float)(0.5 * (a - (s - acc[2])));
    }
}

extern "C" void kernel_launch(void* const* d_in, const int* in_sizes, int n_in,
                              void* d_out, int out_size, void* d_ws, size_t ws_size,
                              hipStream_t stream) {
    const float* Ain    = (const float*)d_in[0];  // (N, N)
    const float* betain = (const float*)d_in[1];  // (N,)
    const float* ain    = (const float*)d_in[2];  // (1,)
    const float* Xin    = (const float*)d_in[3];  // (K, N)
    const float* Cin    = (const float*)d_in[4];  // (N, K)
    float* out = (float*)d_out;

    char* ws = (char*)d_ws;
    float*          E    = (float*)(ws + 0);                 // 4 KB
    double*         acc  = (double*)(ws + 4096);             // 3 doubles (acc[2] = diag sp)
    float*          mC   = (float*)(ws + 4160);
    float*          sC   = (float*)(ws + 4288);
    float*          M    = (float*)(ws + 4608);              // 4 KB
    float*          f    = (float*)(ws + 8704);              // 32 KB
    float*          part = (float*)(ws + 49152);             // 16 KB (2048 x float2)
    unsigned short* Xh   = (unsigned short*)(ws + 65536);    // 512 KB
    unsigned short* Wh   = (unsigned short*)(ws + 589824);   // 512 KB
    unsigned short* Wt2  = (unsigned short*)(ws + 1114112);  // 512 KB (W^T bf16 [K][N])
    float*          Xt   = (float*)(ws + 1638400);           // 1 MB (f32 [N][K])
    float*          Xs   = (float*)(ws + 2686976);           // 1 MB
    // total ~3.7 MB

    hipMemsetAsync(ws, 0, 4128, stream);  // zero E + 3 double accs

    kc_colstats<<<KK, 256, 0, stream>>>(Cin, mC, sC);
    kx_softmax<<<NN / 256, 256, 0, stream>>>(Xin, Xs);
    ke_E<<<256, 1024, 0, stream>>>(Xs, Cin, mC, sC, E);
    km_M<<<1, 1024, 0, stream>>>(E, M);
    kp_prep<<<NN / 256, 256, 0, stream>>>(Xin, betain, ain, M, f, Xt, Xh, Wh, Wt2, acc);
    k_uni<<<2048, 256, 0, stream>>>(Ain, f, Xt, Xh, Wh, Wt2, part);
    kz_final<<<1, 1024, 0, stream>>>(part, acc, out);
}

// Round 8
// 501.116 us; speedup vs baseline: 1.0571x; 1.0571x over previous
//
#include <hip/hip_runtime.h>
#include <hip/hip_bf16.h>

#define NN 8192
#define KK 32

typedef __attribute__((ext_vector_type(8))) short short8v;   // 8 bf16 in 4 VGPRs
typedef __attribute__((ext_vector_type(4))) float float4v;   // MFMA 16x16 acc

__device__ __forceinline__ float wave_reduce_sum(float v) {
    #pragma unroll
    for (int off = 32; off > 0; off >>= 1) v += __shfl_down(v, off);
    return v;
}
__device__ __forceinline__ unsigned short f2bf(float x) {  // RNE fp32->bf16
    unsigned int u = __float_as_uint(x);
    return (unsigned short)((u + 0x7fffu + ((u >> 16) & 1u)) >> 16);
}
__device__ __forceinline__ float bf2f(unsigned short h) {
    return __uint_as_float(((unsigned int)h) << 16);
}

// ---------- K0: sC[l] = sum_n exp(C[n][l]) — no max pass (|C|<~6, exp safe) ----------
__global__ void kc_sum(const float* __restrict__ C, float* __restrict__ sC) {
    const int t = threadIdx.x;        // 256
    const int col = t & 31, rg = t >> 5;
    const int row0 = blockIdx.x * 128;   // 64 blocks x 128 rows
    float p = 0.f;
    #pragma unroll
    for (int u = 0; u < 16; ++u)
        p += __expf(C[(size_t)(row0 + u * 8 + rg) * KK + col]);  // coalesced 1KB/wave
    __shared__ float ps[8][32];
    ps[rg][col] = p;
    __syncthreads();
    if (t < 32) {
        float s = 0.f;
        #pragma unroll
        for (int u = 0; u < 8; ++u) s += ps[u][t];
        atomicAdd(&sC[t], s);
    }
}

// ---------- K1: column softmax of X (K x N) -> Xs ----------
__global__ void kx_softmax(const float* __restrict__ X, float* __restrict__ Xs) {
    const int n = blockIdx.x * 256 + threadIdx.x;
    float e[KK];
    float m = -INFINITY;
    #pragma unroll
    for (int k = 0; k < KK; ++k) {
        e[k] = X[(size_t)k * NN + n];
        m = fmaxf(m, e[k]);
    }
    float s = 0.f;
    #pragma unroll
    for (int k = 0; k < KK; ++k) {
        e[k] = __expf(e[k] - m);
        s += e[k];
    }
    const float r = 1.f / s;
    #pragma unroll
    for (int k = 0; k < KK; ++k) Xs[(size_t)k * NN + n] = e[k] * r;
}

// ---------- K2: E = Xs @ softmax(C), softmax via exp(c)/sC ----------
__global__ void ke_E(const float* __restrict__ Xs, const float* __restrict__ C,
                     const float* __restrict__ sC, float* __restrict__ E) {
    __shared__ float xsl[KK * 33];
    __shared__ float cql[32 * 33];
    __shared__ float rsCl[KK];
    const int tid = threadIdx.x;     // 1024
    if (tid < KK) rsCl[tid] = 1.f / sC[tid];
    const int k = tid & 31, l = tid >> 5;
    const int nb = blockIdx.x * 32;
    __syncthreads();
    xsl[(tid >> 5) * 33 + (tid & 31)] = Xs[(size_t)(tid >> 5) * NN + nb + (tid & 31)];
    const float cv = C[(size_t)nb * KK + tid];
    cql[(tid >> 5) * 33 + (tid & 31)] = __expf(cv) * rsCl[tid & 31];
    __syncthreads();
    float acc = 0.f;
    #pragma unroll
    for (int n = 0; n < 32; ++n)
        acc = fmaf(xsl[k * 33 + n], cql[n * 33 + l], acc);
    atomicAdd(&E[k * KK + l], acc);
}

// ---------- K3: M = E^T E ----------
__global__ void km_M(const float* __restrict__ E, float* __restrict__ M) {
    __shared__ float el[KK * 33];
    const int tid = threadIdx.x;   // 1024
    el[(tid >> 5) * 33 + (tid & 31)] = E[tid];
    __syncthreads();
    const int l1 = tid & 31, l2 = tid >> 5;
    float acc = 0.f;
    #pragma unroll
    for (int kk = 0; kk < KK; ++kk)
        acc = fmaf(el[kk * 33 + l1], el[kk * 33 + l2], acc);
    M[tid] = acc;
}

// ---------- K4: prep: f, Xt f32[N][K], Xh/Wh bf16[N][K], Bh bf16[48][N], diag sp ----------
// Bh rows: 0..31 = w^T, 32 = 1.0, 33 = f_hi, 34 = f_lo, 35..47 = 0
__global__ void kp_prep(const float* __restrict__ X, const float* __restrict__ beta,
                        const float* __restrict__ a_ptr, const float* __restrict__ Mm,
                        float* __restrict__ f, float* __restrict__ Xt,
                        unsigned short* __restrict__ Xh, unsigned short* __restrict__ Wh,
                        unsigned short* __restrict__ Bh,
                        double* __restrict__ acc) {
    __shared__ float Ml[KK * KK];
    const int tid = threadIdx.x;  // 256
    #pragma unroll
    for (int u = 0; u < 4; ++u) Ml[tid + 256 * u] = Mm[tid + 256 * u];
    __syncthreads();
    const int n = blockIdx.x * 256 + tid;
    float x[KK], v[KK];
    #pragma unroll
    for (int k = 0; k < KK; ++k) x[k] = X[(size_t)k * NN + n];
    const float a = a_ptr[0];
    const float two_a = 2.f * a;
    #pragma unroll
    for (int l = 0; l < KK; ++l) {
        float s = 0.f;
        #pragma unroll
        for (int k = 0; k < KK; ++k) s = fmaf(Ml[l * KK + k], x[k], s);
        v[l] = two_a * s;                     // w = 2a M x
    }
    float q2 = 0.f;
    #pragma unroll
    for (int l = 0; l < KK; ++l) q2 = fmaf(x[l], v[l], q2);
    const float b = beta[n];
    const float fn = b - 0.5f * q2;           // f = beta - a x^T M x
    f[n] = fn;

    union PK { unsigned short u[8]; short8v s; };
    PK xh, wh;
    #pragma unroll
    for (int g = 0; g < 4; ++g) {
        #pragma unroll
        for (int e = 0; e < 8; ++e) {
            const int k = g * 8 + e;
            Xt[(size_t)n * KK + k] = x[k];
            xh.u[e] = f2bf(x[k]);
            wh.u[e] = f2bf(v[k]);
            Bh[(size_t)k * NN + n] = wh.u[e];    // coalesced per-k column write
        }
        *(short8v*)&Xh[(size_t)n * KK + g * 8] = xh.s;
        *(short8v*)&Wh[(size_t)n * KK + g * 8] = wh.s;
    }
    Bh[(size_t)32 * NN + n] = 0x3F80;            // 1.0
    const unsigned short hf = f2bf(fn);
    Bh[(size_t)33 * NN + n] = hf;
    Bh[(size_t)34 * NN + n] = f2bf(fn - bf2f(hf));
    #pragma unroll
    for (int k = 35; k < 48; ++k) Bh[(size_t)k * NN + n] = 0;

    // diagonal softplus: theta_ii = 2*beta_i exactly (z_ii = 0)
    const float th = 2.f * b;
    float sp = fmaxf(th, 0.f) + __logf(1.f + __expf(-fabsf(th)));
    sp = wave_reduce_sum(sp);
    if ((tid & 63) == 0) atomicAdd(&acc[2], (double)sp);
}

// ---------- K5a: A-stream kernel. Wave = 16 i x 512 j. P = A @ [W | 1 | f_hi | f_lo]
// 3 MFMAs per 16x32 fp32 A-tile; epilogue once per wave. ----------
__global__ __launch_bounds__(256, 6) void k_A(
    const float* __restrict__ A, const float* __restrict__ f,
    const float* __restrict__ Xt, const unsigned short* __restrict__ Bh,
    float* __restrict__ part) {
    const int tid  = threadIdx.x;
    const int lane = tid & 63;
    const int l15  = lane & 15;
    const int klo2 = (lane >> 4) << 3;
    const int r0   = (lane >> 4) << 2;
    const int wid  = blockIdx.x * 4 + (tid >> 6);
    const int ibase = (wid >> 4) << 4;    // 512 i-tiles of 16 rows
    const int jc    = (wid & 15) << 9;    // 16 j-chunks of 512

    float4v c0 = {0.f, 0.f, 0.f, 0.f}, c1 = c0, c2 = c0;
    const float* arow = &A[(size_t)(ibase + l15) * NN + jc + klo2];
    const unsigned short* b0p = &Bh[(size_t)l15 * NN + jc + klo2];
    const unsigned short* b1p = &Bh[(size_t)(16 + l15) * NN + jc + klo2];
    const unsigned short* b2p = &Bh[(size_t)(32 + l15) * NN + jc + klo2];

    #pragma unroll 2
    for (int jt = 0; jt < 16; ++jt) {
        const float4 a0 = *(const float4*)(arow + jt * 32);
        const float4 a1 = *(const float4*)(arow + jt * 32 + 4);
        union { unsigned int u[4]; short8v s8; } af;   // bf16 truncation: exact for {0,1}
        af.u[0] = __builtin_amdgcn_perm(__float_as_uint(a0.y), __float_as_uint(a0.x), 0x07060302u);
        af.u[1] = __builtin_amdgcn_perm(__float_as_uint(a0.w), __float_as_uint(a0.z), 0x07060302u);
        af.u[2] = __builtin_amdgcn_perm(__float_as_uint(a1.y), __float_as_uint(a1.x), 0x07060302u);
        af.u[3] = __builtin_amdgcn_perm(__float_as_uint(a1.w), __float_as_uint(a1.z), 0x07060302u);
        const short8v b0 = *(const short8v*)(b0p + jt * 32);
        const short8v b1 = *(const short8v*)(b1p + jt * 32);
        const short8v b2 = *(const short8v*)(b2p + jt * 32);
        c0 = __builtin_amdgcn_mfma_f32_16x16x32_bf16(af.s8, b0, c0, 0, 0, 0);
        c1 = __builtin_amdgcn_mfma_f32_16x16x32_bf16(af.s8, b1, c1, 0, 0, 0);
        c2 = __builtin_amdgcn_mfma_f32_16x16x32_bf16(af.s8, b2, c2, 0, 0, 0);
    }

    // epilogue: accA = sum_k x[i][k] P[i][k] + f_i*P[i][32] + P[i][33] + P[i][34]
    float acc = 0.f;
    #pragma unroll
    for (int r = 0; r < 4; ++r) {
        const int row = ibase + r0 + r;
        acc += Xt[(size_t)row * KK + l15] * c0[r];
        acc += Xt[(size_t)row * KK + 16 + l15] * c1[r];
        const float fv = f[row];
        const float mult = (l15 == 0) ? fv : ((l15 < 3) ? 1.f : 0.f);
        acc += mult * c2[r];
    }

    acc = wave_reduce_sum(acc);
    __shared__ float rA[4];
    if (lane == 0) rA[tid >> 6] = acc;
    __syncthreads();
    if (tid == 0) part[blockIdx.x] = rA[0] + rA[1] + rA[2] + rA[3];
}

// ---------- K5b: softplus kernel. Wave = 16 i x 512 j; zero A traffic. ----------
__global__ __launch_bounds__(256, 8) void k_S(
    const float* __restrict__ f, const unsigned short* __restrict__ Xh,
    const unsigned short* __restrict__ Wh, float* __restrict__ partS) {
    const int tid  = threadIdx.x;
    const int lane = tid & 63;
    const int l15  = lane & 15;
    const int klo2 = (lane >> 4) << 3;
    const int r0   = (lane >> 4) << 2;
    const int wid  = blockIdx.x * 4 + (tid >> 6);
    const int ibase = (wid >> 4) << 4;    // 512 i-tiles
    const int jc    = (wid & 15) << 9;    // 16 j-chunks of 512

    const short8v xh = *(const short8v*)&Xh[(size_t)(ibase + l15) * KK + klo2];
    float fS[4];
    #pragma unroll
    for (int r = 0; r < 4; ++r) fS[r] = f[ibase + r0 + r];

    float accS = 0.f;
    #pragma unroll 2
    for (int u = 0; u < 32; ++u) {
        const int jb = jc + (u << 4);
        const short8v wf = *(const short8v*)&Wh[(size_t)(jb + l15) * KK + klo2];
        const float fj = f[jb + l15];
        float4v d = {0.f, 0.f, 0.f, 0.f};
        d = __builtin_amdgcn_mfma_f32_16x16x32_bf16(xh, wf, d, 0, 0, 0);
        #pragma unroll
        for (int r = 0; r < 4; ++r) {
            const float th = fS[r] + fj + d[r];
            accS += fmaxf(th, 0.f) + __logf(1.f + __expf(-fabsf(th)));
        }
    }

    accS = wave_reduce_sum(accS);
    __shared__ float rS[4];
    if (lane == 0) rS[tid >> 6] = accS;
    __syncthreads();
    if (tid == 0) partS[blockIdx.x] = rS[0] + rS[1] + rS[2] + rS[3];
}

// ---------- K6: final deterministic reduction ----------
__global__ __launch_bounds__(1024) void kz_final(const float* __restrict__ part,
                                                 const float* __restrict__ partS,
                                                 const double* __restrict__ acc,
                                                 float* __restrict__ out) {
    const int t = threadIdx.x;  // 1024 threads
    double dA = (double)part[t]  + (double)part[t + 1024];
    double dS = (double)partS[t] + (double)partS[t + 1024];
    #pragma unroll
    for (int off = 32; off > 0; off >>= 1) {
        dA += __shfl_down(dA, off);
        dS += __shfl_down(dS, off);
    }
    __shared__ double sA[16], sS[16];
    if ((t & 63) == 0) { sA[t >> 6] = dA; sS[t >> 6] = dS; }
    __syncthreads();
    if (t == 0) {
        double a = 0.0, s = 0.0;
        #pragma unroll
        for (int u = 0; u < 16; ++u) { a += sA[u]; s += sS[u]; }
        out[0] = (float)(0.5 * (a - (s - acc[2])));
    }
}

extern "C" void kernel_launch(void* const* d_in, const int* in_sizes, int n_in,
                              void* d_out, int out_size, void* d_ws, size_t ws_size,
                              hipStream_t stream) {
    const float* Ain    = (const float*)d_in[0];  // (N, N)
    const float* betain = (const float*)d_in[1];  // (N,)
    const float* ain    = (const float*)d_in[2];  // (1,)
    const float* Xin    = (const float*)d_in[3];  // (K, N)
    const float* Cin    = (const float*)d_in[4];  // (N, K)
    float* out = (float*)d_out;

    char* ws = (char*)d_ws;
    float*          E     = (float*)(ws + 0);                 // 4 KB
    double*         acc   = (double*)(ws + 4096);             // 3 doubles
    float*          sC    = (float*)(ws + 4224);              // 128 B
    float*          f     = (float*)(ws + 8704);              // 32 KB
    float*          part  = (float*)(ws + 49152);             // 8 KB
    float*          partS = (float*)(ws + 57344);             // 8 KB
    unsigned short* Xh    = (unsigned short*)(ws + 65536);    // 512 KB
    unsigned short* Wh    = (unsigned short*)(ws + 589824);   // 512 KB
    float*          Xt    = (float*)(ws + 1114112);           // 1 MB
    unsigned short* Bh    = (unsigned short*)(ws + 2162688);  // 768 KB (48 x N bf16)
    float*          Xs    = (float*)(ws + 2949120);           // 1 MB
    float*          M     = (float*)(ws + 3997696);           // 4 KB
    // total ~4 MB

    hipMemsetAsync(ws, 0, 4352, stream);  // zero E + accs + sC

    kc_sum<<<64, 256, 0, stream>>>(Cin, sC);
    kx_softmax<<<NN / 256, 256, 0, stream>>>(Xin, Xs);
    ke_E<<<256, 1024, 0, stream>>>(Xs, Cin, sC, E);
    km_M<<<1, 1024, 0, stream>>>(E, M);
    kp_prep<<<NN / 256, 256, 0, stream>>>(Xin, betain, ain, M, f, Xt, Xh, Wh, Bh, acc);
    k_S<<<2048, 256, 0, stream>>>(f, Xh, Wh, partS);
    k_A<<<2048, 256, 0, stream>>>(Ain, f, Xt, Bh, part);
    kz_final<<<1, 1024, 0, stream>>>(part, partS, acc, out);
}

// Round 9
// 409.750 us; speedup vs baseline: 1.2928x; 1.2230x over previous
//
#include <hip/hip_runtime.h>
#include <hip/hip_bf16.h>

#define NN 8192
#define KK 32

typedef __attribute__((ext_vector_type(8))) short short8v;   // 8 bf16 in 4 VGPRs
typedef __attribute__((ext_vector_type(4))) float float4v;   // MFMA 16x16 acc

__device__ __forceinline__ float wave_reduce_sum(float v) {
    #pragma unroll
    for (int off = 32; off > 0; off >>= 1) v += __shfl_down(v, off);
    return v;
}
__device__ __forceinline__ unsigned short f2bf(float x) {  // RNE fp32->bf16
    unsigned int u = __float_as_uint(x);
    return (unsigned short)((u + 0x7fffu + ((u >> 16) & 1u)) >> 16);
}

// ---------- K1: fused E' = (exp X / colsum) @ exp(C), plus sC[l] = sum_n exp(C[n][l])
// E = E' / diag(sC) is folded into M in kp_prep. 256 blocks x 256 thr, one 32-n tile each.
// |X|,|C| ~ N(0,1) (<~6) so exp without max-shift is safe in fp32.
__global__ __launch_bounds__(256) void kE(const float* __restrict__ X,
                                          const float* __restrict__ C,
                                          float* __restrict__ Ep,
                                          float* __restrict__ sC) {
    __shared__ float xe[KK * 33];   // exp(X[k][n]) [k][n]
    __shared__ float ce[32 * 33];   // exp(C[n][l]) [n][l]
    __shared__ float xs[32];        // 1 / colsum_k exp(X[k][n])
    const int tid = threadIdx.x;
    const int r = tid >> 5, q = tid & 31;
    const int nb = blockIdx.x * 32;
    #pragma unroll
    for (int u = 0; u < 4; ++u) {
        xe[(r + 8 * u) * 33 + q] = __expf(X[(size_t)(r + 8 * u) * NN + nb + q]);
        ce[(r + 8 * u) * 33 + q] = __expf(C[(size_t)(nb + r + 8 * u) * KK + q]);
    }
    __syncthreads();
    if (tid < 32) {
        float s = 0.f;
        #pragma unroll
        for (int k = 0; k < 32; ++k) s += xe[k * 33 + tid];
        xs[tid] = 1.f / s;
    } else if (tid < 64) {
        const int l = tid - 32;
        float s = 0.f;
        #pragma unroll
        for (int n = 0; n < 32; ++n) s += ce[n * 33 + l];
        atomicAdd(&sC[l], s);
    }
    __syncthreads();
    #pragma unroll
    for (int u = 0; u < 4; ++u) {
        const int k = r + 8 * u;
        float acc = 0.f;
        #pragma unroll
        for (int n = 0; n < 32; ++n)
            acc = fmaf(xe[k * 33 + n] * xs[n], ce[n * 33 + q], acc);
        atomicAdd(&Ep[k * KK + q], acc);
    }
}

// ---------- K2: prep. Computes M = D^-1 E'^T E' D^-1 locally (E' is 4KB, L2-hot),
// then per-node f, Xh, Wh bf16, and the diagonal-softplus correction. ----------
__global__ __launch_bounds__(256) void kp_prep(
    const float* __restrict__ X, const float* __restrict__ beta,
    const float* __restrict__ a_ptr, const float* __restrict__ Ep,
    const float* __restrict__ sC,
    float* __restrict__ f, unsigned short* __restrict__ Xh,
    unsigned short* __restrict__ Wh, double* __restrict__ acc) {
    __shared__ float el[KK * 33];   // E'[k][l]
    __shared__ float rs[32];
    __shared__ float Ml[KK * KK];
    const int tid = threadIdx.x;  // 256
    const int r = tid >> 5, q = tid & 31;
    #pragma unroll
    for (int u = 0; u < 4; ++u)
        el[(r + 8 * u) * 33 + q] = Ep[(r + 8 * u) * KK + q];
    if (tid < 32) rs[tid] = 1.f / sC[tid];
    __syncthreads();
    #pragma unroll
    for (int u = 0; u < 4; ++u) {
        const int l1 = r + 8 * u;
        float m = 0.f;
        #pragma unroll
        for (int k = 0; k < KK; ++k)
            m = fmaf(el[k * 33 + l1], el[k * 33 + q], m);
        Ml[l1 * KK + q] = m * rs[l1] * rs[q];
    }
    __syncthreads();

    const int n = blockIdx.x * 256 + tid;
    float x[KK], v[KK];
    #pragma unroll
    for (int k = 0; k < KK; ++k) x[k] = X[(size_t)k * NN + n];
    const float a = a_ptr[0];
    const float two_a = 2.f * a;
    #pragma unroll
    for (int l = 0; l < KK; ++l) {
        float s = 0.f;
        #pragma unroll
        for (int k = 0; k < KK; ++k) s = fmaf(Ml[l * KK + k], x[k], s);
        v[l] = two_a * s;                     // w = 2a M x
    }
    float q2 = 0.f;
    #pragma unroll
    for (int l = 0; l < KK; ++l) q2 = fmaf(x[l], v[l], q2);
    const float b = beta[n];
    const float fn = b - 0.5f * q2;           // f = beta - a x^T M x
    f[n] = fn;

    union PK { unsigned short u[8]; short8v s; };
    PK xh, wh;
    #pragma unroll
    for (int g = 0; g < 4; ++g) {
        #pragma unroll
        for (int e = 0; e < 8; ++e) {
            const int k = g * 8 + e;
            xh.u[e] = f2bf(x[k]);
            wh.u[e] = f2bf(v[k]);
        }
        *(short8v*)&Xh[(size_t)n * KK + g * 8] = xh.s;
        *(short8v*)&Wh[(size_t)n * KK + g * 8] = wh.s;
    }
    // diagonal softplus: theta_ii = 2*beta_i exactly (z_ii = 0)
    const float th = 2.f * b;
    float sp = fmaxf(th, 0.f) + __logf(1.f + __expf(-fabsf(th)));
    sp = wave_reduce_sum(sp);
    if ((tid & 63) == 0) atomicAdd(&acc[2], (double)sp);
}

// ---------- K3: unified pair kernel, wave = 32 i x 256 j, single bf16 MFMA ----------
// 8192 waves: 256 i-tiles (32 rows) x 32 j-chunks (256 cols)
__global__ __launch_bounds__(256, 6) void k_pair(
    const float* __restrict__ A, const float* __restrict__ f,
    const unsigned short* __restrict__ Xh, const unsigned short* __restrict__ Wh,
    float* __restrict__ part) {
    const int tid  = threadIdx.x;
    const int lane = tid & 63;
    const int l15  = lane & 15;
    const int klo  = (lane >> 4) << 3;
    const int r0   = (lane >> 4) << 2;
    const int wid  = blockIdx.x * 4 + (tid >> 6);
    const int ibase = (wid >> 5) << 5;   // 256 i-tiles of 32 rows
    const int jc    = (wid & 31) << 8;   // 32 j-chunks of 256

    const short8v xh0 = *(const short8v*)&Xh[(size_t)(ibase + l15) * KK + klo];
    const short8v xh1 = *(const short8v*)&Xh[(size_t)(ibase + 16 + l15) * KK + klo];
    float fr[2][4];
    #pragma unroll
    for (int s = 0; s < 2; ++s)
        #pragma unroll
        for (int r = 0; r < 4; ++r) fr[s][r] = f[ibase + 16 * s + r0 + r];

    float accA = 0.f, accS = 0.f;
    #pragma unroll 2
    for (int jt = 0; jt < 16; ++jt) {
        const int jb = jc + (jt << 4);
        const short8v wf = *(const short8v*)&Wh[(size_t)(jb + l15) * KK + klo];
        const float fj = f[jb + l15];
        #pragma unroll
        for (int s = 0; s < 2; ++s) {
            float av[4];
            #pragma unroll
            for (int r = 0; r < 4; ++r)
                av[r] = A[(size_t)(ibase + 16 * s + r0 + r) * NN + jb + l15];
            float4v d = {0.f, 0.f, 0.f, 0.f};
            d = __builtin_amdgcn_mfma_f32_16x16x32_bf16(s ? xh1 : xh0, wf, d, 0, 0, 0);
            #pragma unroll
            for (int r = 0; r < 4; ++r) {
                const float th = fr[s][r] + fj + d[r];
                accA = fmaf(th, av[r], accA);
                accS += fmaxf(th, 0.f) + __logf(1.f + __expf(-fabsf(th)));
            }
        }
    }

    accA = wave_reduce_sum(accA);
    accS = wave_reduce_sum(accS);
    __shared__ float rA[4], rS[4];
    if (lane == 0) { rA[tid >> 6] = accA; rS[tid >> 6] = accS; }
    __syncthreads();
    if (tid == 0) {
        part[blockIdx.x * 2]     = rA[0] + rA[1] + rA[2] + rA[3];
        part[blockIdx.x * 2 + 1] = rS[0] + rS[1] + rS[2] + rS[3];
    }
}

// ---------- K4: final deterministic reduction of 2048 block partials ----------
__global__ __launch_bounds__(1024) void kz_final(const float* __restrict__ part,
                                                 const double* __restrict__ acc,
                                                 float* __restrict__ out) {
    const int t = threadIdx.x;  // 1024 threads
    double dA = (double)part[2 * t]     + (double)part[2 * (t + 1024)];
    double dS = (double)part[2 * t + 1] + (double)part[2 * (t + 1024) + 1];
    #pragma unroll
    for (int off = 32; off > 0; off >>= 1) {
        dA += __shfl_down(dA, off);
        dS += __shfl_down(dS, off);
    }
    __shared__ double sA[16], sS[16];
    if ((t & 63) == 0) { sA[t >> 6] = dA; sS[t >> 6] = dS; }
    __syncthreads();
    if (t == 0) {
        double a = 0.0, s = 0.0;
        #pragma unroll
        for (int u = 0; u < 16; ++u) { a += sA[u]; s += sS[u]; }
        out[0] = (float)(0.5 * (a - (s - acc[2])));
    }
}

extern "C" void kernel_launch(void* const* d_in, const int* in_sizes, int n_in,
                              void* d_out, int out_size, void* d_ws, size_t ws_size,
                              hipStream_t stream) {
    const float* Ain    = (const float*)d_in[0];  // (N, N)
    const float* betain = (const float*)d_in[1];  // (N,)
    const float* ain    = (const float*)d_in[2];  // (1,)
    const float* Xin    = (const float*)d_in[3];  // (K, N)
    const float* Cin    = (const float*)d_in[4];  // (N, K)
    float* out = (float*)d_out;

    char* ws = (char*)d_ws;
    float*          Ep    = (float*)(ws + 0);                 // 4 KB (E' unnormalized)
    double*         acc   = (double*)(ws + 4096);             // 3 doubles (acc[2] = diag sp)
    float*          sC    = (float*)(ws + 4224);              // 128 B
    float*          f     = (float*)(ws + 8704);              // 32 KB
    float*          part  = (float*)(ws + 49152);             // 16 KB (2048 x float2)
    unsigned short* Xh    = (unsigned short*)(ws + 65536);    // 512 KB
    unsigned short* Wh    = (unsigned short*)(ws + 589824);   // 512 KB
    // total ~1.1 MB

    hipMemsetAsync(ws, 0, 4352, stream);  // zero Ep + accs + sC

    kE<<<256, 256, 0, stream>>>(Xin, Cin, Ep, sC);
    kp_prep<<<NN / 256, 256, 0, stream>>>(Xin, betain, ain, Ep, sC, f, Xh, Wh, acc);
    k_pair<<<2048, 256, 0, stream>>>(Ain, f, Xh, Wh, part);
    kz_final<<<1, 1024, 0, stream>>>(part, acc, out);
}